// Round 7
// baseline (44.513 us; speedup 1.0000x reference)
//
#include <hip/hip_runtime.h>
#include <stdint.h>

// Problem constants
constexpr int Dn = 10000;
constexpr int Bn = 128;
constexpr int Wn = 512;
constexpr int Hn = 128;
constexpr int CAP = 65536;       // ambiguous-list capacity
constexpr int NTILES = 157;      // ceil(10000/64) d-tiles of N=64
constexpr int TPW = 5;           // d-tiles per wave: 32 groups * 5 = 160 >= 157

typedef float  f32x4  __attribute__((ext_vector_type(4)));
typedef short  bf16x8 __attribute__((ext_vector_type(8)));  // 8 bf16 (4 VGPRs)

__device__ inline uint16_t f32_to_bf16(float f) {           // RNE
    uint32_t u = __builtin_bit_cast(uint32_t, f);
    return (uint16_t)((u + 0x7FFFu + ((u >> 16) & 1u)) >> 16);
}
__device__ inline float bf16_to_f32(uint16_t h) {
    uint32_t u = ((uint32_t)h) << 16;
    return __builtin_bit_cast(float, u);
}

// ---------------------------------------------------------------------------
// Kernel 1 (fused pre-pass):
//  blocks 0..511  : h-reduction for (b, w-quarter). float4 loads, fp64 accum,
//                   LDS slice-combine. Writes sT64[b][w] (for exact fixup) and
//                   aHi/aLo -- bf16 hi/lo split of S in MFMA A-fragment layout
//                   idx = ((ktile*8+mtile)*64 + lane)*8 + j with
//                   lane = (b&15)|(((w>>3)&3)<<4), j = w&7.
//  blocks 512..1136: pack W signs TRANSPOSED: bitsT[d*16+g] bit j =
//                   (W[g*32+j][d] > 0) -- 64B contiguous per d column so the
//                   GEMM loads a whole K-column of masks as 4 dwordx4.
// ---------------------------------------------------------------------------
__global__ __launch_bounds__(256) void prep(const float* __restrict__ x,
                                            const float* __restrict__ wts,
                                            double* __restrict__ sT64,
                                            uint16_t* __restrict__ aHi,
                                            uint16_t* __restrict__ aLo,
                                            uint32_t* __restrict__ bitsT,
                                            uint32_t* __restrict__ cnt) {
    int bid = blockIdx.x;
    if (bid == 0 && threadIdx.x == 0) *cnt = 0;
    if (bid < 512) {
        int b  = bid >> 2;
        int w0 = (bid & 3) << 7;            // w-quarter base
        int wc = threadIdx.x & 31;          // float4 column: w = w0 + wc*4
        int hs = threadIdx.x >> 5;          // 8 h-slices of 16
        const f32x4* p = (const f32x4*)(x + (size_t)b * (Hn * Wn)
                                          + (size_t)(hs * 16) * Wn + w0) + wc;
        double a0 = 0, a1 = 0, a2 = 0, a3 = 0;
        #pragma unroll
        for (int h = 0; h < 16; ++h) {
            f32x4 f = p[(size_t)h * (Wn / 4)];
            a0 += (double)f.x; a1 += (double)f.y;
            a2 += (double)f.z; a3 += (double)f.w;
        }
        __shared__ double red[8][128];
        red[hs][wc * 4 + 0] = a0;
        red[hs][wc * 4 + 1] = a1;
        red[hs][wc * 4 + 2] = a2;
        red[hs][wc * 4 + 3] = a3;
        __syncthreads();
        if (threadIdx.x < 128) {
            int wl = threadIdx.x;
            double s = 0.0;
            #pragma unroll
            for (int k = 0; k < 8; ++k) s += red[k][wl];   // fixed order
            int w = w0 + wl;
            sT64[(size_t)b * Wn + w] = s;
            float s32 = (float)s;
            uint16_t hi = f32_to_bf16(s32);
            float hif = bf16_to_f32(hi);
            uint16_t lo = f32_to_bf16(s32 - hif);          // residual capture
            int ktile = w >> 5;
            int mtile = b >> 4;
            int lane  = (b & 15) | (((w >> 3) & 3) << 4);
            int j     = w & 7;
            size_t idx = (size_t)((ktile * 8 + mtile) * 64 + lane) * 8 + j;
            aHi[idx] = hi;
            aLo[idx] = lo;
        }
    } else {
        int idx = (bid - 512) * 256 + (int)threadIdx.x;    // 0 .. 159999 exactly
        int g = idx / Dn;
        int d = idx - g * Dn;
        uint32_t m = 0;
        #pragma unroll
        for (int j = 0; j < 32; ++j)
            m |= (wts[(size_t)(g * 32 + j) * Dn + d] > 0.0f) ? (1u << j) : 0u;
        bitsT[(size_t)d * 16 + g] = m;                     // transposed layout
    }
}

// ---------------------------------------------------------------------------
// Kernel 2: MFMA GEMM, A register-resident, d streamed.
// grid (32, 8), 64 threads (1 wave). blockIdx.y = mt (16 b's); wave loads its
// A fragments for ALL K once (ah[16], al[16] = 128 VGPR, static indexing),
// then iterates TPW d-tiles of N=64. Per tile: 16 dwordx4 mask loads
// (bitsT column-contiguous, one latency wait), then 16g x 4nt x {hi,lo}
// = 128 MFMA with everything in registers. Epilogue: sign + ambiguous
// compact (|v| <= 0.25; bf16-split worst-case error ~0.02 << 0.25).
// ---------------------------------------------------------------------------
__global__ __launch_bounds__(64, 1) void gemm_mfma(const uint32_t* __restrict__ bitsT,
                                                   const uint16_t* __restrict__ aHi,
                                                   const uint16_t* __restrict__ aLo,
                                                   uint32_t* __restrict__ cnt,
                                                   uint32_t* __restrict__ list,
                                                   float* __restrict__ out) {
    int lane = (int)threadIdx.x;       // 0..63
    int mt = blockIdx.y;               // 0..7 -> b-range mt*16..+15
    int ln = lane & 15;
    int lh = lane >> 4;
    int sh = lh * 8;

    const bf16x8* Ah = (const bf16x8*)aHi;
    const bf16x8* Al = (const bf16x8*)aLo;
    bf16x8 ah[16], al[16];
    #pragma unroll
    for (int g = 0; g < 16; ++g) {
        int fi = (g * 8 + mt) * 64 + lane;
        ah[g] = Ah[fi];
        al[g] = Al[fi];
    }

    int t1 = blockIdx.x * TPW + TPW;
    if (t1 > NTILES) t1 = NTILES;
    for (int t = blockIdx.x * TPW; t < t1; ++t) {
        int dbase = t * 64;
        // load all 4 nt x 16 g mask words for this tile (contiguous 64B/d)
        uint32_t wrd[4][16];
        #pragma unroll
        for (int nt = 0; nt < 4; ++nt) {
            int d = dbase + nt * 16 + ln;
            int dc = d < Dn ? d : Dn - 1;
            const uint4* wp = (const uint4*)(bitsT + (size_t)dc * 16);
            #pragma unroll
            for (int q = 0; q < 4; ++q) {
                uint4 v = wp[q];
                wrd[nt][4 * q + 0] = v.x; wrd[nt][4 * q + 1] = v.y;
                wrd[nt][4 * q + 2] = v.z; wrd[nt][4 * q + 3] = v.w;
            }
        }
        f32x4 acc[4];
        #pragma unroll
        for (int nt = 0; nt < 4; ++nt) acc[nt] = (f32x4){0.f, 0.f, 0.f, 0.f};
        #pragma unroll
        for (int g = 0; g < 16; ++g) {
            #pragma unroll
            for (int nt = 0; nt < 4; ++nt) {
                uint32_t t8 = (wrd[nt][g] >> sh) & 0xFFu;
                // bit=1 -> +1.0 (0x3F80), bit=0 -> -1.0 (0xBF80): XOR sign bit
                int bw0 = (int)(0xBF80BF80u ^ (((t8 & 1u) << 15) | ((t8 & 2u) << 30)));
                int bw1 = (int)(0xBF80BF80u ^ ((((t8 >> 2) & 1u) << 15) | (((t8 >> 3) & 1u) << 31)));
                int bw2 = (int)(0xBF80BF80u ^ ((((t8 >> 4) & 1u) << 15) | (((t8 >> 5) & 1u) << 31)));
                int bw3 = (int)(0xBF80BF80u ^ ((((t8 >> 6) & 1u) << 15) | (((t8 >> 7) & 1u) << 31)));
                union { int i[4]; bf16x8 v; } bu;
                bu.i[0] = bw0; bu.i[1] = bw1; bu.i[2] = bw2; bu.i[3] = bw3;
                bf16x8 bf = bu.v;
                acc[nt] = __builtin_amdgcn_mfma_f32_16x16x32_bf16(ah[g], bf, acc[nt], 0, 0, 0);
                acc[nt] = __builtin_amdgcn_mfma_f32_16x16x32_bf16(al[g], bf, acc[nt], 0, 0, 0);
            }
        }
        // Epilogue: C/D layout col = lane&15, row = (lane>>4)*4 + reg.
        #pragma unroll
        for (int nt = 0; nt < 4; ++nt) {
            int d = dbase + nt * 16 + ln;
            if (d < Dn) {
                #pragma unroll
                for (int r = 0; r < 4; ++r) {
                    int b = mt * 16 + lh * 4 + r;
                    float v = acc[nt][r];
                    size_t o = (size_t)b * Dn + d;
                    out[o] = v > 0.0f ? 1.0f : -1.0f;
                    if (fabsf(v) <= 0.25f) {
                        uint32_t u = atomicAdd(cnt, 1u);
                        if (u < CAP) list[u] = (uint32_t)o;   // fixup overwrites
                    }
                }
            }
        }
    }
}

// ---------------------------------------------------------------------------
// Kernel 3: exact fp64 recompute of ambiguous outputs. One wave per item:
// 512 terms over 64 lanes (8 each) from bitsT + L2-resident sT64[b][w]
// (contiguous per item), fp64 butterfly reduce. ~1000 items expected.
// ---------------------------------------------------------------------------
__global__ __launch_bounds__(256) void fixup_exact(const uint32_t* __restrict__ cnt,
                                                   const uint32_t* __restrict__ list,
                                                   const uint32_t* __restrict__ bitsT,
                                                   const double* __restrict__ sT64,
                                                   float* __restrict__ out) {
    int lane = threadIdx.x & 63;
    int wave = blockIdx.x * 4 + (threadIdx.x >> 6);   // 0..1023
    uint32_t n = *cnt;
    if (n > CAP) n = CAP;
    for (uint32_t item = wave; item < n; item += 1024) {
        int i = (int)list[item];
        int b = i / Dn;
        int d = i - b * Dn;
        double a = 0.0;
        #pragma unroll
        for (int k = 0; k < 8; ++k) {
            int w = lane + 64 * k;
            uint32_t m = bitsT[(size_t)d * 16 + (w >> 5)];
            double s = sT64[(size_t)b * Wn + w];
            a += ((m >> (w & 31)) & 1u) ? s : -s;
        }
        #pragma unroll
        for (int off = 32; off >= 1; off >>= 1)
            a += __shfl_xor(a, off, 64);
        if (lane == 0)
            out[i] = (a > 0.0) ? 1.0f : ((a < 0.0) ? -1.0f : 0.0f);
    }
}

// ---------------------------------------------------------------------------
extern "C" void kernel_launch(void* const* d_in, const int* in_sizes, int n_in,
                              void* d_out, int out_size, void* d_ws, size_t ws_size,
                              hipStream_t stream) {
    const float* x   = (const float*)d_in[0];   // (128,128,512) f32
    const float* wts = (const float*)d_in[1];   // (512,10000)  f32, values +-1
    float* out = (float*)d_out;                 // (128,10000)  f32 signs
    char* ws = (char*)d_ws;

    // workspace layout (~1.7 MB total)
    double*   sT64  = (double*)(ws);                  // 128*512*8 = 524,288 B
    uint16_t* aHi   = (uint16_t*)(ws + 524288);       // 65536*2   = 131,072 B
    uint16_t* aLo   = (uint16_t*)(ws + 655360);       // 131,072 B
    uint32_t* bitsT = (uint32_t*)(ws + 786432);       // 10000*16*4 = 640,000 B
    uint32_t* cnt   = (uint32_t*)(ws + 1426432);      // 256 B (padded)
    uint32_t* list  = (uint32_t*)(ws + 1426688);      // 262,144 B

    prep<<<1137, 256, 0, stream>>>(x, wts, sT64, aHi, aLo, bitsT, cnt);
    gemm_mfma<<<dim3(32, 8), 64, 0, stream>>>(bitsT, aHi, aLo, cnt, list, out);
    fixup_exact<<<256, 256, 0, stream>>>(cnt, list, bitsT, sT64, out);
}

// Round 8
// 38.658 us; speedup vs baseline: 1.1515x; 1.1515x over previous
//
#include <hip/hip_runtime.h>
#include <stdint.h>

// Problem constants
constexpr int Dn = 10000;
constexpr int Bn = 128;
constexpr int Wn = 512;
constexpr int Hn = 128;
constexpr int CAP = 65536;       // ambiguous-list capacity
constexpr int NTILES = 157;      // ceil(10000/64) d-tiles of N=64

typedef float  f32x4  __attribute__((ext_vector_type(4)));
typedef short  bf16x8 __attribute__((ext_vector_type(8)));  // 8 bf16 (4 VGPRs)

__device__ inline uint16_t f32_to_bf16(float f) {           // RNE
    uint32_t u = __builtin_bit_cast(uint32_t, f);
    return (uint16_t)((u + 0x7FFFu + ((u >> 16) & 1u)) >> 16);
}
__device__ inline float bf16_to_f32(uint16_t h) {
    uint32_t u = ((uint32_t)h) << 16;
    return __builtin_bit_cast(float, u);
}

// ---------------------------------------------------------------------------
// Kernel 1 (fused pre-pass):
//  blocks 0..511  : h-reduction for (b, w-quarter). float4 loads, fp64 accum,
//                   LDS slice-combine. Writes sT64[b][w] (for exact fixup) and
//                   aHi/aLo -- bf16 hi/lo split of S in MFMA A-fragment layout
//                   idx = ((ktile*8+mtile)*64 + lane)*8 + j with
//                   lane = (b&15)|(((w>>3)&3)<<4), j = w&7.
//  blocks 512..1136: pack W signs TRANSPOSED: bitsT[d*16+g] bit j =
//                   (W[g*32+j][d] > 0) -- 64B contiguous per d column so the
//                   GEMM loads a whole K-column of masks as 4 dwordx4.
// ---------------------------------------------------------------------------
__global__ __launch_bounds__(256) void prep(const float* __restrict__ x,
                                            const float* __restrict__ wts,
                                            double* __restrict__ sT64,
                                            uint16_t* __restrict__ aHi,
                                            uint16_t* __restrict__ aLo,
                                            uint32_t* __restrict__ bitsT,
                                            uint32_t* __restrict__ cnt) {
    int bid = blockIdx.x;
    if (bid == 0 && threadIdx.x == 0) *cnt = 0;
    if (bid < 512) {
        int b  = bid >> 2;
        int w0 = (bid & 3) << 7;            // w-quarter base
        int wc = threadIdx.x & 31;          // float4 column: w = w0 + wc*4
        int hs = threadIdx.x >> 5;          // 8 h-slices of 16
        const f32x4* p = (const f32x4*)(x + (size_t)b * (Hn * Wn)
                                          + (size_t)(hs * 16) * Wn + w0) + wc;
        double a0 = 0, a1 = 0, a2 = 0, a3 = 0;
        #pragma unroll
        for (int h = 0; h < 16; ++h) {
            f32x4 f = p[(size_t)h * (Wn / 4)];
            a0 += (double)f.x; a1 += (double)f.y;
            a2 += (double)f.z; a3 += (double)f.w;
        }
        __shared__ double red[8][128];
        red[hs][wc * 4 + 0] = a0;
        red[hs][wc * 4 + 1] = a1;
        red[hs][wc * 4 + 2] = a2;
        red[hs][wc * 4 + 3] = a3;
        __syncthreads();
        if (threadIdx.x < 128) {
            int wl = threadIdx.x;
            double s = 0.0;
            #pragma unroll
            for (int k = 0; k < 8; ++k) s += red[k][wl];   // fixed order
            int w = w0 + wl;
            sT64[(size_t)b * Wn + w] = s;
            float s32 = (float)s;
            uint16_t hi = f32_to_bf16(s32);
            float hif = bf16_to_f32(hi);
            uint16_t lo = f32_to_bf16(s32 - hif);          // residual capture
            int ktile = w >> 5;
            int mtile = b >> 4;
            int lane  = (b & 15) | (((w >> 3) & 3) << 4);
            int j     = w & 7;
            size_t idx = (size_t)((ktile * 8 + mtile) * 64 + lane) * 8 + j;
            aHi[idx] = hi;
            aLo[idx] = lo;
        }
    } else {
        int idx = (bid - 512) * 256 + (int)threadIdx.x;    // 0 .. 159999 exactly
        int g = idx / Dn;
        int d = idx - g * Dn;
        uint32_t m = 0;
        #pragma unroll
        for (int j = 0; j < 32; ++j)
            m |= (wts[(size_t)(g * 32 + j) * Dn + d] > 0.0f) ? (1u << j) : 0u;
        bitsT[(size_t)d * 16 + g] = m;                     // transposed layout
    }
}

// ---------------------------------------------------------------------------
// Kernel 2: MFMA GEMM, one wave-task per (d-tile, mt).
// grid (40, 8), 256 threads = 4 waves; wave w owns tile t = bx*4+w (N=64),
// mt = blockIdx.y (16 b's). Per wave: 16 dwordx4 mask loads (bitsT column-
// contiguous), then per g (unrolled): 2 dwordx4 A-fragment loads from
// L2-resident aHi/aLo + 8 MFMA into 4 independent acc chains. Peak regs
// ~125 (wrd 64 + acc 16 + pipelined A window) -- no spill, no big live
// arrays. 1280 waves = 5/CU so latency overlaps across waves.
// Epilogue: sign + ambiguous compact (|v| <= 0.25).
// ---------------------------------------------------------------------------
__global__ __launch_bounds__(256) void gemm_mfma(const uint32_t* __restrict__ bitsT,
                                                 const uint16_t* __restrict__ aHi,
                                                 const uint16_t* __restrict__ aLo,
                                                 uint32_t* __restrict__ cnt,
                                                 uint32_t* __restrict__ list,
                                                 float* __restrict__ out) {
    int lane = (int)threadIdx.x & 63;
    int wid  = (int)threadIdx.x >> 6;
    int t    = blockIdx.x * 4 + wid;     // d-tile index
    if (t >= NTILES) return;             // no barriers in this kernel
    int mt = blockIdx.y;                 // b-range mt*16..+15
    int ln = lane & 15;
    int lh = lane >> 4;
    int sh = lh * 8;
    int dbase = t * 64;

    // Load all 4 nt x 16 g mask words for this tile (contiguous 64B per d).
    uint32_t wrd[4][16];
    #pragma unroll
    for (int nt = 0; nt < 4; ++nt) {
        int d = dbase + nt * 16 + ln;
        int dc = d < Dn ? d : Dn - 1;    // clamp (tail tile only)
        const uint4* wp = (const uint4*)(bitsT + (size_t)dc * 16);
        #pragma unroll
        for (int q = 0; q < 4; ++q) {
            uint4 v = wp[q];
            wrd[nt][4 * q + 0] = v.x; wrd[nt][4 * q + 1] = v.y;
            wrd[nt][4 * q + 2] = v.z; wrd[nt][4 * q + 3] = v.w;
        }
    }

    f32x4 acc[4];
    #pragma unroll
    for (int nt = 0; nt < 4; ++nt) acc[nt] = (f32x4){0.f, 0.f, 0.f, 0.f};

    const bf16x8* Ah = (const bf16x8*)aHi;
    const bf16x8* Al = (const bf16x8*)aLo;

    #pragma unroll
    for (int g = 0; g < 16; ++g) {
        int fi = (g * 8 + mt) * 64 + lane;
        bf16x8 ah = Ah[fi];              // L2-resident (A = 256 KB total)
        bf16x8 al = Al[fi];
        #pragma unroll
        for (int nt = 0; nt < 4; ++nt) {
            uint32_t t8 = (wrd[nt][g] >> sh) & 0xFFu;
            // bit=1 -> +1.0 (0x3F80), bit=0 -> -1.0 (0xBF80): XOR sign bit
            int bw0 = (int)(0xBF80BF80u ^ (((t8 & 1u) << 15) | ((t8 & 2u) << 30)));
            int bw1 = (int)(0xBF80BF80u ^ ((((t8 >> 2) & 1u) << 15) | (((t8 >> 3) & 1u) << 31)));
            int bw2 = (int)(0xBF80BF80u ^ ((((t8 >> 4) & 1u) << 15) | (((t8 >> 5) & 1u) << 31)));
            int bw3 = (int)(0xBF80BF80u ^ ((((t8 >> 6) & 1u) << 15) | (((t8 >> 7) & 1u) << 31)));
            union { int i[4]; bf16x8 v; } bu;
            bu.i[0] = bw0; bu.i[1] = bw1; bu.i[2] = bw2; bu.i[3] = bw3;
            bf16x8 bf = bu.v;
            acc[nt] = __builtin_amdgcn_mfma_f32_16x16x32_bf16(ah, bf, acc[nt], 0, 0, 0);
            acc[nt] = __builtin_amdgcn_mfma_f32_16x16x32_bf16(al, bf, acc[nt], 0, 0, 0);
        }
    }

    // Epilogue: C/D layout col = lane&15, row = (lane>>4)*4 + reg.
    #pragma unroll
    for (int nt = 0; nt < 4; ++nt) {
        int d = dbase + nt * 16 + ln;
        if (d < Dn) {
            #pragma unroll
            for (int r = 0; r < 4; ++r) {
                int b = mt * 16 + lh * 4 + r;
                float v = acc[nt][r];
                size_t o = (size_t)b * Dn + d;
                out[o] = v > 0.0f ? 1.0f : -1.0f;
                if (fabsf(v) <= 0.25f) {
                    uint32_t u = atomicAdd(cnt, 1u);
                    if (u < CAP) list[u] = (uint32_t)o;   // fixup overwrites
                }
            }
        }
    }
}

// ---------------------------------------------------------------------------
// Kernel 3: exact fp64 recompute of ambiguous outputs. One wave per item:
// 512 terms over 64 lanes (8 each) from bitsT + L2-resident sT64[b][w]
// (contiguous per item), fp64 butterfly reduce. ~1000 items expected.
// ---------------------------------------------------------------------------
__global__ __launch_bounds__(256) void fixup_exact(const uint32_t* __restrict__ cnt,
                                                   const uint32_t* __restrict__ list,
                                                   const uint32_t* __restrict__ bitsT,
                                                   const double* __restrict__ sT64,
                                                   float* __restrict__ out) {
    int lane = threadIdx.x & 63;
    int wave = blockIdx.x * 4 + (threadIdx.x >> 6);   // 0..1023
    uint32_t n = *cnt;
    if (n > CAP) n = CAP;
    for (uint32_t item = wave; item < n; item += 1024) {
        int i = (int)list[item];
        int b = i / Dn;
        int d = i - b * Dn;
        double a = 0.0;
        #pragma unroll
        for (int k = 0; k < 8; ++k) {
            int w = lane + 64 * k;
            uint32_t m = bitsT[(size_t)d * 16 + (w >> 5)];
            double s = sT64[(size_t)b * Wn + w];
            a += ((m >> (w & 31)) & 1u) ? s : -s;
        }
        #pragma unroll
        for (int off = 32; off >= 1; off >>= 1)
            a += __shfl_xor(a, off, 64);
        if (lane == 0)
            out[i] = (a > 0.0) ? 1.0f : ((a < 0.0) ? -1.0f : 0.0f);
    }
}

// ---------------------------------------------------------------------------
extern "C" void kernel_launch(void* const* d_in, const int* in_sizes, int n_in,
                              void* d_out, int out_size, void* d_ws, size_t ws_size,
                              hipStream_t stream) {
    const float* x   = (const float*)d_in[0];   // (128,128,512) f32
    const float* wts = (const float*)d_in[1];   // (512,10000)  f32, values +-1
    float* out = (float*)d_out;                 // (128,10000)  f32 signs
    char* ws = (char*)d_ws;

    // workspace layout (~1.7 MB total)
    double*   sT64  = (double*)(ws);                  // 128*512*8 = 524,288 B
    uint16_t* aHi   = (uint16_t*)(ws + 524288);       // 65536*2   = 131,072 B
    uint16_t* aLo   = (uint16_t*)(ws + 655360);       // 131,072 B
    uint32_t* bitsT = (uint32_t*)(ws + 786432);       // 10000*16*4 = 640,000 B
    uint32_t* cnt   = (uint32_t*)(ws + 1426432);      // 256 B (padded)
    uint32_t* list  = (uint32_t*)(ws + 1426688);      // 262,144 B

    prep<<<1137, 256, 0, stream>>>(x, wts, sT64, aHi, aLo, bitsT, cnt);
    gemm_mfma<<<dim3(40, 8), 256, 0, stream>>>(bitsT, aHi, aLo, cnt, list, out);
    fixup_exact<<<256, 256, 0, stream>>>(cnt, list, bitsT, sT64, out);
}

// Round 9
// 31.022 us; speedup vs baseline: 1.4349x; 1.2462x over previous
//
#include <hip/hip_runtime.h>
#include <stdint.h>

// Problem constants
constexpr int Dn = 10000;
constexpr int Bn = 128;
constexpr int Wn = 512;
constexpr int Hn = 128;
constexpr int NTILES = 157;      // ceil(10000/64) d-tiles of N=64

typedef float  f32x4  __attribute__((ext_vector_type(4)));
typedef short  bf16x8 __attribute__((ext_vector_type(8)));  // 8 bf16 (4 VGPRs)

__device__ inline uint16_t f32_to_bf16(float f) {           // RNE
    uint32_t u = __builtin_bit_cast(uint32_t, f);
    return (uint16_t)((u + 0x7FFFu + ((u >> 16) & 1u)) >> 16);
}
__device__ inline float bf16_to_f32(uint16_t h) {
    uint32_t u = ((uint32_t)h) << 16;
    return __builtin_bit_cast(float, u);
}

// ---------------------------------------------------------------------------
// Kernel 1 (fused pre-pass):
//  blocks 0..511  : h-reduction for (b, w-quarter). float4 loads, fp64 accum,
//                   LDS slice-combine. Writes sT64[b][w] (for exact fixup) and
//                   aHi/aLo -- bf16 hi/lo split of S in MFMA A-fragment layout
//                   idx = ((ktile*8+mtile)*64 + lane)*8 + j with
//                   lane = (b&15)|(((w>>3)&3)<<4), j = w&7.
//  blocks 512..1136: pack W signs TRANSPOSED: bitsT[d*16+g] bit j =
//                   (W[g*32+j][d] > 0) -- 64B contiguous per d column so the
//                   GEMM loads a whole K-column of masks as 4 dwordx4.
// ---------------------------------------------------------------------------
__global__ __launch_bounds__(256) void prep(const float* __restrict__ x,
                                            const float* __restrict__ wts,
                                            double* __restrict__ sT64,
                                            uint16_t* __restrict__ aHi,
                                            uint16_t* __restrict__ aLo,
                                            uint32_t* __restrict__ bitsT) {
    int bid = blockIdx.x;
    if (bid < 512) {
        int b  = bid >> 2;
        int w0 = (bid & 3) << 7;            // w-quarter base
        int wc = threadIdx.x & 31;          // float4 column: w = w0 + wc*4
        int hs = threadIdx.x >> 5;          // 8 h-slices of 16
        const f32x4* p = (const f32x4*)(x + (size_t)b * (Hn * Wn)
                                          + (size_t)(hs * 16) * Wn + w0) + wc;
        double a0 = 0, a1 = 0, a2 = 0, a3 = 0;
        #pragma unroll
        for (int h = 0; h < 16; ++h) {
            f32x4 f = p[(size_t)h * (Wn / 4)];
            a0 += (double)f.x; a1 += (double)f.y;
            a2 += (double)f.z; a3 += (double)f.w;
        }
        __shared__ double red[8][128];
        red[hs][wc * 4 + 0] = a0;
        red[hs][wc * 4 + 1] = a1;
        red[hs][wc * 4 + 2] = a2;
        red[hs][wc * 4 + 3] = a3;
        __syncthreads();
        if (threadIdx.x < 128) {
            int wl = threadIdx.x;
            double s = 0.0;
            #pragma unroll
            for (int k = 0; k < 8; ++k) s += red[k][wl];   // fixed order
            int w = w0 + wl;
            sT64[(size_t)b * Wn + w] = s;
            float s32 = (float)s;
            uint16_t hi = f32_to_bf16(s32);
            float hif = bf16_to_f32(hi);
            uint16_t lo = f32_to_bf16(s32 - hif);          // residual capture
            int ktile = w >> 5;
            int mtile = b >> 4;
            int lane  = (b & 15) | (((w >> 3) & 3) << 4);
            int j     = w & 7;
            size_t idx = (size_t)((ktile * 8 + mtile) * 64 + lane) * 8 + j;
            aHi[idx] = hi;
            aLo[idx] = lo;
        }
    } else {
        int idx = (bid - 512) * 256 + (int)threadIdx.x;    // 0 .. 159999 exactly
        int g = idx / Dn;
        int d = idx - g * Dn;
        uint32_t m = 0;
        #pragma unroll
        for (int j = 0; j < 32; ++j)
            m |= (wts[(size_t)(g * 32 + j) * Dn + d] > 0.0f) ? (1u << j) : 0u;
        bitsT[(size_t)d * 16 + g] = m;                     // transposed layout
    }
}

// ---------------------------------------------------------------------------
// Kernel 2: MFMA GEMM + sign + INLINE wave-cooperative exact fixup.
// grid (40, 8), 256 threads = 4 waves; wave w owns d-tile t = bx*4+w (N=64),
// mt = blockIdx.y (16 b's). Per wave: 16 dwordx4 mask loads, then per g:
// 2 dwordx4 A loads (L2-resident) + 8 MFMA into 4 acc chains.
// Epilogue per (nt,r): store sign guess; __ballot the ambiguous lanes
// (|v| <= 0.25; bf16-split worst-case error ~0.02 << 0.25; ~0.8 hits/wave);
// for each set bit all 64 lanes recompute that (b,d) exactly in fp64 from
// sT64 (coalesced) + bitsT (broadcast), butterfly-reduce, owner lane
// overwrites its own guess (same-lane program order => exact value final).
// ---------------------------------------------------------------------------
__global__ __launch_bounds__(256) void gemm_mfma(const uint32_t* __restrict__ bitsT,
                                                 const uint16_t* __restrict__ aHi,
                                                 const uint16_t* __restrict__ aLo,
                                                 const double* __restrict__ sT64,
                                                 float* __restrict__ out) {
    int lane = (int)threadIdx.x & 63;
    int wid  = (int)threadIdx.x >> 6;
    int t    = blockIdx.x * 4 + wid;     // d-tile index
    if (t >= NTILES) return;             // no barriers in this kernel
    int mt = blockIdx.y;                 // b-range mt*16..+15
    int ln = lane & 15;
    int lh = lane >> 4;
    int sh = lh * 8;
    int dbase = t * 64;

    // Load all 4 nt x 16 g mask words for this tile (contiguous 64B per d).
    uint32_t wrd[4][16];
    #pragma unroll
    for (int nt = 0; nt < 4; ++nt) {
        int d = dbase + nt * 16 + ln;
        int dc = d < Dn ? d : Dn - 1;    // clamp (tail tile only)
        const uint4* wp = (const uint4*)(bitsT + (size_t)dc * 16);
        #pragma unroll
        for (int q = 0; q < 4; ++q) {
            uint4 v = wp[q];
            wrd[nt][4 * q + 0] = v.x; wrd[nt][4 * q + 1] = v.y;
            wrd[nt][4 * q + 2] = v.z; wrd[nt][4 * q + 3] = v.w;
        }
    }

    f32x4 acc[4];
    #pragma unroll
    for (int nt = 0; nt < 4; ++nt) acc[nt] = (f32x4){0.f, 0.f, 0.f, 0.f};

    const bf16x8* Ah = (const bf16x8*)aHi;
    const bf16x8* Al = (const bf16x8*)aLo;

    #pragma unroll
    for (int g = 0; g < 16; ++g) {
        int fi = (g * 8 + mt) * 64 + lane;
        bf16x8 ah = Ah[fi];              // L2-resident (A = 256 KB total)
        bf16x8 al = Al[fi];
        #pragma unroll
        for (int nt = 0; nt < 4; ++nt) {
            uint32_t t8 = (wrd[nt][g] >> sh) & 0xFFu;
            // bit=1 -> +1.0 (0x3F80), bit=0 -> -1.0 (0xBF80): XOR sign bit
            int bw0 = (int)(0xBF80BF80u ^ (((t8 & 1u) << 15) | ((t8 & 2u) << 30)));
            int bw1 = (int)(0xBF80BF80u ^ ((((t8 >> 2) & 1u) << 15) | (((t8 >> 3) & 1u) << 31)));
            int bw2 = (int)(0xBF80BF80u ^ ((((t8 >> 4) & 1u) << 15) | (((t8 >> 5) & 1u) << 31)));
            int bw3 = (int)(0xBF80BF80u ^ ((((t8 >> 6) & 1u) << 15) | (((t8 >> 7) & 1u) << 31)));
            union { int i[4]; bf16x8 v; } bu;
            bu.i[0] = bw0; bu.i[1] = bw1; bu.i[2] = bw2; bu.i[3] = bw3;
            bf16x8 bf = bu.v;
            acc[nt] = __builtin_amdgcn_mfma_f32_16x16x32_bf16(ah, bf, acc[nt], 0, 0, 0);
            acc[nt] = __builtin_amdgcn_mfma_f32_16x16x32_bf16(al, bf, acc[nt], 0, 0, 0);
        }
    }

    // Epilogue. C/D layout: col = lane&15, row = (lane>>4)*4 + reg.
    #pragma unroll
    for (int nt = 0; nt < 4; ++nt) {
        int d = dbase + nt * 16 + ln;
        bool valid = d < Dn;
        #pragma unroll
        for (int r = 0; r < 4; ++r) {
            int b = mt * 16 + lh * 4 + r;
            float v = acc[nt][r];
            if (valid) out[(size_t)b * Dn + d] = v > 0.0f ? 1.0f : -1.0f;
            unsigned long long mask = __ballot(valid && fabsf(v) <= 0.25f);
            while (mask) {
                int l = __ffsll((long long)mask) - 1;
                mask &= mask - 1;
                int bl = mt * 16 + (l >> 4) * 4 + r;
                int dl = dbase + nt * 16 + (l & 15);
                const double* srow = sT64 + (size_t)bl * Wn;
                double a = 0.0;
                #pragma unroll
                for (int k = 0; k < 8; ++k) {
                    int w = lane + 64 * k;
                    uint32_t mw = bitsT[(size_t)dl * 16 + (w >> 5)];
                    double s = srow[w];
                    a += ((mw >> (w & 31)) & 1u) ? s : -s;
                }
                #pragma unroll
                for (int off = 32; off >= 1; off >>= 1)
                    a += __shfl_xor(a, off, 64);
                if (lane == l)          // owner overwrites its own guess
                    out[(size_t)bl * Dn + dl] = (a > 0.0) ? 1.0f : ((a < 0.0) ? -1.0f : 0.0f);
            }
        }
    }
}

// ---------------------------------------------------------------------------
extern "C" void kernel_launch(void* const* d_in, const int* in_sizes, int n_in,
                              void* d_out, int out_size, void* d_ws, size_t ws_size,
                              hipStream_t stream) {
    const float* x   = (const float*)d_in[0];   // (128,128,512) f32
    const float* wts = (const float*)d_in[1];   // (512,10000)  f32, values +-1
    float* out = (float*)d_out;                 // (128,10000)  f32 signs
    char* ws = (char*)d_ws;

    // workspace layout (~1.43 MB total)
    double*   sT64  = (double*)(ws);                  // 128*512*8 = 524,288 B
    uint16_t* aHi   = (uint16_t*)(ws + 524288);       // 65536*2   = 131,072 B
    uint16_t* aLo   = (uint16_t*)(ws + 655360);       // 131,072 B
    uint32_t* bitsT = (uint32_t*)(ws + 786432);       // 10000*16*4 = 640,000 B

    prep<<<1137, 256, 0, stream>>>(x, wts, sT64, aHi, aLo, bitsT);
    gemm_mfma<<<dim3(40, 8), 256, 0, stream>>>(bitsT, aHi, aLo, sT64, out);
}